// Round 7
// baseline (135.947 us; speedup 1.0000x reference)
//
#include <hip/hip_runtime.h>

#define NELEM 8388608    // 8*256*64*64
#define M_GAP 8e-5f      // validated rounds 4-5 for bf16 2-plane 3-MFMA

typedef short s16x8 __attribute__((ext_vector_type(8)));
typedef float f32x4 __attribute__((ext_vector_type(4)));

__device__ __forceinline__ unsigned short bf16r(float f) {
  unsigned u = __float_as_uint(f);
  return (unsigned short)((u + 0x7fffu + ((u >> 16) & 1u)) >> 16);
}
__device__ __forceinline__ float bf16f(unsigned short h) {
  return __uint_as_float(((unsigned)h) << 16);
}

// numpy pairwise sum of squares, 128-block: 8 accumulators stride 8,
// combined ((r0+r1)+(r2+r3))+((r4+r5)+(r6+r7)). All single-rounded f32.
__device__ __forceinline__ float pw128_sq(const float* p, int s) {
  float r[8];
#pragma unroll
  for (int j = 0; j < 8; ++j) { float v = p[j * s]; r[j] = __fmul_rn(v, v); }
#pragma unroll
  for (int i = 8; i < 128; i += 8) {
#pragma unroll
    for (int j = 0; j < 8; ++j) {
      float v = p[(i + j) * s];
      r[j] = __fadd_rn(r[j], __fmul_rn(v, v));
    }
  }
  return __fadd_rn(__fadd_rn(__fadd_rn(r[0], r[1]), __fadd_rn(r[2], r[3])),
                   __fadd_rn(__fadd_rn(r[4], r[5]), __fadd_rn(r[6], r[7])));
}
__device__ __forceinline__ float np_sumsq256(const float* p, int s) {
  return __fadd_rn(pw128_sq(p, s), pw128_sq(p + 128 * s, s));
}

// ---- prep: pre-swizzled bf16 hi/lo codebook image (32-code tiles) ----
// tile jt in [0,32): 16384 shorts (32 KB): h-plane [0,8192):
//   img[jj*256 + (c ^ (jj<<3))], l-plane at +8192 shorts. jj = code&31.
__global__ __launch_bounds__(256)
void vq_prep(const float* __restrict__ cb, unsigned short* __restrict__ cbimg,
             float* __restrict__ cbT, float* __restrict__ Bsg,
             unsigned* __restrict__ cnt, float* __restrict__ loss) {
  int gid = blockIdx.x * 256 + threadIdx.x;   // 0..4095
  if (gid == 0) { *cnt = 0u; *loss = 0.0f; }
  int j = gid >> 2, qt = gid & 3;
  const float4* row4 = reinterpret_cast<const float4*>(cb + (size_t)j * 256 + qt * 64);
  int jt = j >> 5, jj = j & 31;
  unsigned short* baseh = cbimg + (size_t)jt * 16384 + jj * 256;
  unsigned short* basel = baseh + 8192;
  int sw = jj << 3;
#pragma unroll
  for (int m = 0; m < 8; ++m) {               // 8 consecutive c per group
    int c0 = qt * 64 + m * 8;
    float4 va = row4[m * 2];
    float4 vb = row4[m * 2 + 1];
    float v[8] = {va.x, va.y, va.z, va.w, vb.x, vb.y, vb.z, vb.w};
    s16x8 hv, lv;
#pragma unroll
    for (int q = 0; q < 8; ++q) {
      unsigned short h = bf16r(v[q]);
      hv[q] = (short)h;
      lv[q] = (short)bf16r(v[q] - bf16f(h));
      cbT[(size_t)(c0 + q) * 1024 + j] = v[q];
    }
    int e = c0 ^ sw;                          // c0 8-aligned, sw bits 3..7
    *reinterpret_cast<s16x8*>(baseh + e) = hv;
    *reinterpret_cast<s16x8*>(basel + e) = lv;
  }
  if (qt == 0) Bsg[j] = np_sumsq256(cb + (size_t)j * 256, 1);
}

// ---- fast: 256 blocks x 128 rows, 4 waves x 32 rows, bf16 3-MFMA, 2 blk/CU
__global__ __launch_bounds__(256, 2)
void vq_fast(const float* __restrict__ z, const float* __restrict__ cb,
             const unsigned short* __restrict__ cbimg,
             const float* __restrict__ Bsg,
             float* __restrict__ zq, float* __restrict__ loss,
             float* __restrict__ idxo,
             unsigned* __restrict__ list, unsigned* __restrict__ cnt) {
  __shared__ __align__(16) unsigned char buf[66560];  // zt[256][65] / 2x32KB B / ldsF
  __shared__ float BsL[1024];
  __shared__ float part[16][64];
  __shared__ float rowA[128];
  __shared__ int bestj[128];
  __shared__ float bestd[128];
  __shared__ unsigned char flg[128];
  __shared__ float wred[4];

  const int t = threadIdx.x;
  const int bid = blockIdx.x;          // rows n0 = bid*128; (b,h) = bid*2, bid*2+1
  const int lane = t & 63;
  const int wv = t >> 6;               // wave 0..3, rows wv*32..+31
  const int l15 = lane & 15;
  const int lk = lane >> 4;            // 0..3

  float* zt = reinterpret_cast<float*>(buf);   // [256 c][65] f32 during A-stage
  s16x8 ah[2][8], al[2][8];            // 2 row-subtiles x 8 k-steps, hi/lo planes

  // ---- A staging in halves (64 rows = one (b,h) each) ----
  for (int hp = 0; hp < 2; ++hp) {
    int bh = bid * 2 + hp;
    const float4* z4 = reinterpret_cast<const float4*>(
        z + (size_t)(bh >> 6) * 1048576 + (size_t)(bh & 63) * 64);
    float sq[4] = {0.f, 0.f, 0.f, 0.f};
#pragma unroll
    for (int i = 0; i < 16; ++i) {
      int idx = t + i * 256;           // c = idx>>4, w4 = t&15
      int c = idx >> 4, w4 = idx & 15;
      float4 v = z4[(size_t)c * 1024 + w4];
      zt[c * 65 + w4 * 4 + 0] = v.x;
      zt[c * 65 + w4 * 4 + 1] = v.y;
      zt[c * 65 + w4 * 4 + 2] = v.z;
      zt[c * 65 + w4 * 4 + 3] = v.w;
      sq[0] += v.x * v.x; sq[1] += v.y * v.y;
      sq[2] += v.z * v.z; sq[3] += v.w * v.w;
    }
#pragma unroll
    for (int q = 0; q < 4; ++q) part[t >> 4][(t & 15) * 4 + q] = sq[q];
    __syncthreads();
    if (t < 64) {
      float s = 0.f;
#pragma unroll
      for (int g = 0; g < 16; ++g) s += part[g][t];
      rowA[hp * 64 + t] = s;
    }
    if ((wv >> 1) == hp) {             // waves 0,1 own half 0; waves 2,3 half 1
#pragma unroll
      for (int rs = 0; rs < 2; ++rs) {
        int lr = (wv & 1) * 32 + rs * 16 + l15;   // local row in half
#pragma unroll
        for (int kk = 0; kk < 8; ++kk)
#pragma unroll
          for (int m = 0; m < 8; ++m) {
            float f = zt[(kk * 32 + lk * 8 + m) * 65 + lr];
            unsigned short h = bf16r(f);
            ah[rs][kk][m] = (short)h;
            al[rs][kk][m] = (short)bf16r(f - bf16f(h));
          }
      }
    }
    __syncthreads();
  }

  // ---- stage B tile 0 (linear copy; swizzle baked into cbimg) ----
#pragma unroll
  for (int i = 0; i < 8; ++i) {
    int item = t + i * 256;            // 0..2047 s16x8 items (32 KB)
    *reinterpret_cast<s16x8*>(buf + item * 16) =
        *reinterpret_cast<const s16x8*>((const unsigned char*)cbimg + item * 16);
  }
  for (int i = t; i < 1024; i += 256) BsL[i] = Bsg[i];
  __syncthreads();

  float b1v[2][4], b2v[2][4];
  int b1i[2][4];
#pragma unroll
  for (int rs = 0; rs < 2; ++rs)
#pragma unroll
    for (int r = 0; r < 4; ++r) { b1v[rs][r] = 3.4e38f; b2v[rs][r] = 3.4e38f; b1i[rs][r] = 0; }

  for (int jt = 0; jt < 32; ++jt) {
    const unsigned short* bufH = reinterpret_cast<const unsigned short*>(buf + (jt & 1) * 32768);
    const unsigned short* bufL = bufH + 8192;
    unsigned char* nbuf = buf + ((jt + 1) & 1) * 32768;
    const unsigned char* nsrc = (const unsigned char*)cbimg + (size_t)(jt + 1) * 32768;

    f32x4 acc[2][2];
#pragma unroll
    for (int rs = 0; rs < 2; ++rs)
#pragma unroll
      for (int js = 0; js < 2; ++js) acc[rs][js] = (f32x4){0.f, 0.f, 0.f, 0.f};

    s16x8 g0, g1, g2, g3, g4, g5, g6, g7;
#pragma unroll
    for (int kk = 0; kk < 8; ++kk) {
      if (jt < 31) {
        if (kk == 0) {
          g0 = *reinterpret_cast<const s16x8*>(nsrc + (t + 0) * 16);
          g1 = *reinterpret_cast<const s16x8*>(nsrc + (t + 256) * 16);
          g2 = *reinterpret_cast<const s16x8*>(nsrc + (t + 512) * 16);
          g3 = *reinterpret_cast<const s16x8*>(nsrc + (t + 768) * 16);
        } else if (kk == 2) {
          g4 = *reinterpret_cast<const s16x8*>(nsrc + (t + 1024) * 16);
          g5 = *reinterpret_cast<const s16x8*>(nsrc + (t + 1280) * 16);
          g6 = *reinterpret_cast<const s16x8*>(nsrc + (t + 1536) * 16);
          g7 = *reinterpret_cast<const s16x8*>(nsrc + (t + 1792) * 16);
        }
      }
#pragma unroll
      for (int js = 0; js < 2; ++js) {
        int jj = js * 16 + l15;        // 0..31
        int e = jj * 256 + ((kk * 32 + lk * 8) ^ (jj << 3));
        s16x8 bh = *reinterpret_cast<const s16x8*>(bufH + e);
        s16x8 bl = *reinterpret_cast<const s16x8*>(bufL + e);
#pragma unroll
        for (int rs = 0; rs < 2; ++rs) {
          acc[rs][js] = __builtin_amdgcn_mfma_f32_16x16x32_bf16(al[rs][kk], bh, acc[rs][js], 0, 0, 0);
          acc[rs][js] = __builtin_amdgcn_mfma_f32_16x16x32_bf16(ah[rs][kk], bl, acc[rs][js], 0, 0, 0);
          acc[rs][js] = __builtin_amdgcn_mfma_f32_16x16x32_bf16(ah[rs][kk], bh, acc[rs][js], 0, 0, 0);
        }
      }
      if (jt < 31) {
        if (kk == 4) {
          *reinterpret_cast<s16x8*>(nbuf + (t + 0) * 16) = g0;
          *reinterpret_cast<s16x8*>(nbuf + (t + 256) * 16) = g1;
          *reinterpret_cast<s16x8*>(nbuf + (t + 512) * 16) = g2;
          *reinterpret_cast<s16x8*>(nbuf + (t + 768) * 16) = g3;
        } else if (kk == 6) {
          *reinterpret_cast<s16x8*>(nbuf + (t + 1024) * 16) = g4;
          *reinterpret_cast<s16x8*>(nbuf + (t + 1280) * 16) = g5;
          *reinterpret_cast<s16x8*>(nbuf + (t + 1536) * 16) = g6;
          *reinterpret_cast<s16x8*>(nbuf + (t + 1792) * 16) = g7;
        }
      }
    }

    // scores s = B_j - 2*acc ; top-2, ascending j (first-index ties kept)
#pragma unroll
    for (int js = 0; js < 2; ++js) {
      int j = jt * 32 + js * 16 + l15;
      float Bj = BsL[j];
#pragma unroll
      for (int rs = 0; rs < 2; ++rs)
#pragma unroll
        for (int r = 0; r < 4; ++r) {
          float s = fmaf(-2.0f, acc[rs][js][r], Bj);
          bool lt = s < b1v[rs][r];
          float other = lt ? b1v[rs][r] : s;
          b2v[rs][r] = fminf(b2v[rs][r], other);
          b1v[rs][r] = fminf(b1v[rs][r], s);
          b1i[rs][r] = lt ? j : b1i[rs][r];
        }
    }
    __syncthreads();
  }

  // merge top-2 across the 16 lanes sharing rows
#pragma unroll
  for (int mk = 1; mk < 16; mk <<= 1) {
#pragma unroll
    for (int rs = 0; rs < 2; ++rs)
#pragma unroll
      for (int r = 0; r < 4; ++r) {
        float ov1 = __shfl_xor(b1v[rs][r], mk, 64);
        float ov2 = __shfl_xor(b2v[rs][r], mk, 64);
        int oi1 = __shfl_xor(b1i[rs][r], mk, 64);
        bool lt = ov1 < b1v[rs][r];
        float hi = lt ? b1v[rs][r] : ov1;
        b2v[rs][r] = fminf(fminf(b2v[rs][r], ov2), hi);
        b1v[rs][r] = fminf(b1v[rs][r], ov1);
        b1i[rs][r] = lt ? oi1 : b1i[rs][r];
      }
  }
  if (l15 == 0) {
#pragma unroll
    for (int rs = 0; rs < 2; ++rs)
#pragma unroll
      for (int r = 0; r < 4; ++r) {
        int rr = wv * 32 + rs * 16 + lk * 4 + r;   // D row = (lane>>4)*4 + reg
        bestj[rr] = b1i[rs][r];
        bestd[rr] = b1v[rs][r];
        flg[rr] = (b2v[rs][r] - b1v[rs][r] <= M_GAP) ? 1 : 0;
      }
  }
  __syncthreads();

  if (t < 128) {
    int n = bid * 128 + t;
    idxo[n] = (float)bestj[t];             // provisional for flagged rows
    if (flg[t]) { unsigned pos = atomicAdd(cnt, 1u); list[pos] = (unsigned)n; }
  }

  // loss for unflagged rows: dist^2 = rowA + s_best (tolerance is huge)
  {
    float lv = (t < 128 && !flg[t]) ? (rowA[t] + bestd[t]) : 0.f;
#pragma unroll
    for (int off = 32; off > 0; off >>= 1) lv += __shfl_down(lv, off, 64);
    if (lane == 0) wred[wv] = lv;
  }
  __syncthreads();
  if (t == 0)
    atomicAdd(loss, (wred[0] + wred[1] + wred[2] + wred[3]) * (1.25f / (float)NELEM));

  // ---- zq gather, per half: cb rows -> LDS transpose -> coalesced write ----
  f32x4* ldsF4 = reinterpret_cast<f32x4*>(buf);
  const float* ldsF = reinterpret_cast<const float*>(buf);
  const float4* cb4 = reinterpret_cast<const float4*>(cb);
  for (int hp = 0; hp < 2; ++hp) {
    __syncthreads();
#pragma unroll
    for (int i = 0; i < 16; ++i) {
      int item = t + i * 256;            // rr = item>>6 in [0,64), cc = item&63
      int rr = item >> 6, cc = item & 63;
      float4 v = cb4[(size_t)bestj[hp * 64 + rr] * 64 + cc];
      ldsF4[rr * 64 + (cc ^ ((rr >> 2) & 7))] = (f32x4){v.x, v.y, v.z, v.w};
    }
    __syncthreads();
    int bh = bid * 2 + hp;
    float* zqb = zq + (size_t)(bh >> 6) * 1048576 + (size_t)(bh & 63) * 64;
#pragma unroll
    for (int i = 0; i < 16; ++i) {
      int item = t + i * 256;            // w4 = t&15, c = (t>>4) + 16i
      int w4 = item & 15, c = item >> 4;
      float ov[4];
#pragma unroll
      for (int q = 0; q < 4; ++q) {
        int rr = w4 * 4 + q;
        ov[q] = ldsF[(rr * 64 + ((c >> 2) ^ ((rr >> 2) & 7))) * 4 + (c & 3)];
      }
      *reinterpret_cast<float4*>(zqb + (size_t)c * 4096 + w4 * 4) =
          make_float4(ov[0], ov[1], ov[2], ov[3]);
    }
  }
}

// ---- exact: batched np-chain rescore, 4 flagged rows per block ----
__global__ __launch_bounds__(256)
void vq_exact(const float* __restrict__ z, const float* __restrict__ cb,
              const float* __restrict__ cbT, const float* __restrict__ Bsg,
              const unsigned* __restrict__ list, const unsigned* __restrict__ cnt,
              float* __restrict__ zq, float* __restrict__ loss,
              float* __restrict__ idxo) {
  __shared__ float zr[4][260];
  __shared__ float Anp[4];
  __shared__ int jwin[4];
  __shared__ float rv[256];
  __shared__ int ri[256];
  __shared__ float lred[256];
  const int t = threadIdx.x;
  const unsigned K = *cnt;
  const float4* cbT4 = reinterpret_cast<const float4*>(cbT);

  for (unsigned g = blockIdx.x; g * 4 < K; g += gridDim.x) {
    int nrows = (int)min(4u, K - g * 4);
    __syncthreads();   // guard shared reuse across iterations
    {
      int r = t >> 6, l64 = t & 63;
      if (r < nrows) {
        int n = (int)list[g * 4 + r];
        int b = n >> 12, hw = n & 4095;
        const float* zb = z + (size_t)b * 1048576 + hw;
#pragma unroll
        for (int q = 0; q < 4; ++q) {
          int c = l64 * 4 + q;
          zr[r][c] = zb[(size_t)c * 4096];
        }
      }
    }
    __syncthreads();
    if (t < nrows) Anp[t] = np_sumsq256(&zr[t][0], 1);
    __syncthreads();

    // shared cbT read: per c one float4 (j = 4t..4t+3) feeds all rows
    float acc[4][4];
#pragma unroll
    for (int r = 0; r < 4; ++r)
#pragma unroll
      for (int q = 0; q < 4; ++q) acc[r][q] = 0.f;
    for (int c = 0; c < 256; ++c) {
      float4 bv = cbT4[c * 256 + t];
#pragma unroll
      for (int r = 0; r < 4; ++r) {
        float zc = zr[r][c];
        acc[r][0] = fmaf(zc, bv.x, acc[r][0]);
        acc[r][1] = fmaf(zc, bv.y, acc[r][1]);
        acc[r][2] = fmaf(zc, bv.z, acc[r][2]);
        acc[r][3] = fmaf(zc, bv.w, acc[r][3]);
      }
    }

    // per-row argmin: d = fl(fl(A+B) - 2C), first-index ties
    for (int r = 0; r < nrows; ++r) {
      float A = Anp[r];
      float bvv = 3.4e38f;
      int bii = 0;
#pragma unroll
      for (int q = 0; q < 4; ++q) {
        int j = t * 4 + q;
        float dd = __fsub_rn(__fadd_rn(A, Bsg[j]), __fmul_rn(2.0f, acc[r][q]));
        if (dd < bvv) { bvv = dd; bii = j; }
      }
      rv[t] = bvv; ri[t] = bii;
      __syncthreads();
      for (int s2 = 128; s2 > 0; s2 >>= 1) {
        if (t < s2) {
          float v2 = rv[t + s2]; int i2 = ri[t + s2];
          if (v2 < rv[t] || (v2 == rv[t] && i2 < ri[t])) { rv[t] = v2; ri[t] = i2; }
        }
        __syncthreads();
      }
      if (t == 0) jwin[r] = ri[0];
      __syncthreads();
    }

    // outputs: idx, zq column, loss
    float lacc = 0.f;
    for (int r = 0; r < nrows; ++r) {
      int n = (int)list[g * 4 + r];
      int b = n >> 12, hw = n & 4095;
      int jw = jwin[r];
      float cv = cb[(size_t)jw * 256 + t];
      zq[(size_t)b * 1048576 + (size_t)t * 4096 + hw] = cv;
      if (t == 0) idxo[n] = (float)jw;
      float d = cv - zr[r][t];
      lacc += d * d;
    }
    lred[t] = lacc;
    __syncthreads();
    for (int s2 = 128; s2 > 0; s2 >>= 1) {
      if (t < s2) lred[t] += lred[t + s2];
      __syncthreads();
    }
    if (t == 0) atomicAdd(loss, lred[0] * (1.25f / (float)NELEM));
  }
}

// ---- fallback (round-2 validated all-exact kernel) ----
__global__ __launch_bounds__(256)
void vq_ref(const float* __restrict__ z, const float* __restrict__ cb,
            float* __restrict__ zq, float* __restrict__ loss,
            float* __restrict__ idxo) {
  __shared__ __align__(16) float zt[256 * 64];
  __shared__ __align__(16) float cbt[256 * 64];
  __shared__ float As[64];
  __shared__ float Bs[64];
  __shared__ int bestj[64];
  __shared__ float cand_v[16 * 64];
  __shared__ int cand_i[16 * 64];
  __shared__ double wred[4];
  const int t = threadIdx.x;
  const int wg = t & 15, jg = t >> 4;
  const int bid = blockIdx.x;
  const int b = bid >> 6, h = bid & 63;
  const int n0 = bid * 64;
  const float4* z4 = reinterpret_cast<const float4*>(z + (size_t)b * 256 * 4096 + (size_t)h * 64);
  float4* zt4 = reinterpret_cast<float4*>(zt);
#pragma unroll
  for (int i = 0; i < 16; ++i) {
    int idx4 = t + i * 256;
    zt4[idx4] = z4[(size_t)(idx4 >> 4) * 1024 + (idx4 & 15)];
  }
  __syncthreads();
  if (t < 64) As[t] = np_sumsq256(zt + t, 64);
  float bv[4]; int bi[4];
#pragma unroll
  for (int a = 0; a < 4; ++a) { bv[a] = 3.4e38f; bi[a] = 0; }
  for (int p = 0; p < 16; ++p) {
    __syncthreads();
    const float4* cb4 = reinterpret_cast<const float4*>(cb) + (size_t)p * 64 * 64;
#pragma unroll
    for (int i = 0; i < 16; ++i) {
      int idx4 = t + i * 256;
      int jj = idx4 >> 6, c4 = idx4 & 63;
      float4 v = cb4[idx4];
      cbt[(c4 * 4 + 0) * 64 + jj] = v.x;
      cbt[(c4 * 4 + 1) * 64 + jj] = v.y;
      cbt[(c4 * 4 + 2) * 64 + jj] = v.z;
      cbt[(c4 * 4 + 3) * 64 + jj] = v.w;
    }
    __syncthreads();
    if (t < 64) Bs[t] = np_sumsq256(cbt + t, 64);
    float acc[4][4];
#pragma unroll
    for (int a = 0; a < 4; ++a)
#pragma unroll
      for (int u = 0; u < 4; ++u) acc[a][u] = 0.0f;
    const float4* ztp = reinterpret_cast<const float4*>(zt) + wg;
    const float4* cbp = reinterpret_cast<const float4*>(cbt) + jg;
#pragma unroll 4
    for (int c = 0; c < 256; ++c) {
      float4 zv = ztp[c * 16];
      float4 cv = cbp[c * 16];
      float za[4] = {zv.x, zv.y, zv.z, zv.w};
      float ca[4] = {cv.x, cv.y, cv.z, cv.w};
#pragma unroll
      for (int a = 0; a < 4; ++a)
#pragma unroll
        for (int u = 0; u < 4; ++u) acc[a][u] = fmaf(za[a], ca[u], acc[a][u]);
    }
    __syncthreads();
#pragma unroll
    for (int u = 0; u < 4; ++u) {
      int j = p * 64 + jg * 4 + u;
      float Bju = Bs[jg * 4 + u];
#pragma unroll
      for (int a = 0; a < 4; ++a) {
        float AB = __fadd_rn(As[wg * 4 + a], Bju);
        float dd = __fsub_rn(AB, __fmul_rn(2.0f, acc[a][u]));
        if (dd < bv[a]) { bv[a] = dd; bi[a] = j; }
      }
    }
  }
  __syncthreads();
#pragma unroll
  for (int a = 0; a < 4; ++a) {
    int w = wg * 4 + a;
    cand_v[jg * 64 + w] = bv[a];
    cand_i[jg * 64 + w] = bi[a];
  }
  __syncthreads();
  if (t < 64) {
    float v0 = cand_v[t]; int i0 = cand_i[t];
    for (int g = 1; g < 16; ++g) {
      float v = cand_v[g * 64 + t]; int ii = cand_i[g * 64 + t];
      if (v < v0 || (v == v0 && ii < i0)) { v0 = v; i0 = ii; }
    }
    bestj[t] = i0;
    idxo[n0 + t] = (float)i0;
  }
  __syncthreads();
  double lsum = 0.0;
  float* zqbase = zq + (size_t)b * 256 * 4096 + (size_t)h * 64;
  for (int i = 0; i < 64; ++i) {
    int idx = t + i * 256;
    int c = idx >> 6, w = idx & 63;
    float zvv = zt[c * 64 + w];
    float cvv = cb[(size_t)bestj[w] * 256 + c];
    zqbase[(size_t)c * 4096 + w] = cvv;
    double d = (double)cvv - (double)zvv;
    lsum += d * d;
  }
#pragma unroll
  for (int off = 32; off > 0; off >>= 1) lsum += __shfl_down(lsum, off, 64);
  if ((t & 63) == 0) wred[t >> 6] = lsum;
  __syncthreads();
  if (t == 0) {
    double tot = wred[0] + wred[1] + wred[2] + wred[3];
    atomicAdd(loss, (float)(tot * (1.25 / (double)NELEM)));
  }
}

extern "C" void kernel_launch(void* const* d_in, const int* in_sizes, int n_in,
                              void* d_out, int out_size, void* d_ws, size_t ws_size,
                              hipStream_t stream) {
  (void)in_sizes; (void)n_in; (void)out_size;
  const float* z = (const float*)d_in[0];
  const float* cb = (const float*)d_in[1];
  float* out = (float*)d_out;
  float* zq = out;
  float* loss = out + NELEM;
  float* idxo = out + NELEM + 1;
  if (ws_size < 2236416) {   // scratch too small: validated all-exact path
    hipMemsetAsync(loss, 0, sizeof(float), stream);
    vq_ref<<<512, 256, 0, stream>>>(z, cb, zq, loss, idxo);
    return;
  }
  unsigned char* ws = (unsigned char*)d_ws;
  unsigned* cnt = (unsigned*)ws;                             // 4 B
  float* Bsg = (float*)(ws + 1024);                          // 4 KB
  unsigned* list = (unsigned*)(ws + 8192);                   // 128 KB
  float* cbT = (float*)(ws + 139264);                        // 1 MB
  unsigned short* cbimg = (unsigned short*)(ws + 1187840);   // 1 MB bf16 h/l
  vq_prep<<<16, 256, 0, stream>>>(cb, cbimg, cbT, Bsg, cnt, loss);
  vq_fast<<<256, 256, 0, stream>>>(z, cb, cbimg, Bsg, zq, loss, idxo, list, cnt);
  vq_exact<<<512, 256, 0, stream>>>(z, cb, cbT, Bsg, list, cnt, zq, loss, idxo);
}

// Round 8
// 100.194 us; speedup vs baseline: 1.3568x; 1.3568x over previous
//
#include <hip/hip_runtime.h>
#include <hip/hip_fp16.h>

#define NELEM 8388608    // 8*256*64*64
#define M_GAP 6e-4f      // validated round 6 (fp16 1-plane, x1024 codebook)
#define SCORE_SCALE (-1.0f / 512.0f)

typedef _Float16 f16x8 __attribute__((ext_vector_type(8)));
typedef short s16x8 __attribute__((ext_vector_type(8)));
typedef float f32x4 __attribute__((ext_vector_type(4)));

__device__ __forceinline__ unsigned short bf16r(float f) {
  unsigned u = __float_as_uint(f);
  return (unsigned short)((u + 0x7fffu + ((u >> 16) & 1u)) >> 16);
}
__device__ __forceinline__ float bf16f(unsigned short h) {
  return __uint_as_float(((unsigned)h) << 16);
}

// numpy pairwise sum of squares (n=256): two 128-blocks of 8 accumulators.
__device__ __forceinline__ float pw128_sq(const float* p, int s) {
  float r[8];
#pragma unroll
  for (int j = 0; j < 8; ++j) { float v = p[j * s]; r[j] = __fmul_rn(v, v); }
#pragma unroll
  for (int i = 8; i < 128; i += 8) {
#pragma unroll
    for (int j = 0; j < 8; ++j) {
      float v = p[(i + j) * s];
      r[j] = __fadd_rn(r[j], __fmul_rn(v, v));
    }
  }
  return __fadd_rn(__fadd_rn(__fadd_rn(r[0], r[1]), __fadd_rn(r[2], r[3])),
                   __fadd_rn(__fadd_rn(r[4], r[5]), __fadd_rn(r[6], r[7])));
}
__device__ __forceinline__ float np_sumsq256(const float* p, int s) {
  return __fadd_rn(pw128_sq(p, s), pw128_sq(p + 128 * s, s));
}

// ---- prep: pre-swizzled fp16 (x1024) codebook image, 32-code tiles ----
// tile jt in [0,32): 8192 shorts (16 KB): img[jj*256 + (c ^ (jj<<3))], jj=j&31.
__global__ __launch_bounds__(256)
void vq_prep(const float* __restrict__ cb, unsigned short* __restrict__ cbimg,
             float* __restrict__ cbT, float* __restrict__ Bsg,
             unsigned* __restrict__ cnt, float* __restrict__ loss) {
  int gid = blockIdx.x * 256 + threadIdx.x;   // 0..4095
  if (gid == 0) { *cnt = 0u; *loss = 0.0f; }
  int j = gid >> 2, qt = gid & 3;
  const float4* row4 = reinterpret_cast<const float4*>(cb + (size_t)j * 256 + qt * 64);
  int jt = j >> 5, jj = j & 31;
  unsigned short* baseh = cbimg + (size_t)jt * 8192 + jj * 256;
  int sw = jj << 3;
#pragma unroll
  for (int m = 0; m < 8; ++m) {
    int c0 = qt * 64 + m * 8;
    float4 va = row4[m * 2];
    float4 vb = row4[m * 2 + 1];
    float v[8] = {va.x, va.y, va.z, va.w, vb.x, vb.y, vb.z, vb.w};
    s16x8 hv;
#pragma unroll
    for (int q = 0; q < 8; ++q) {
      hv[q] = (short)__half_as_ushort(__float2half(v[q] * 1024.0f));
      cbT[(size_t)(c0 + q) * 1024 + j] = v[q];
    }
    *reinterpret_cast<s16x8*>(baseh + (c0 ^ sw)) = hv;
  }
  if (qt == 0) Bsg[j] = np_sumsq256(cb + (size_t)j * 256, 1);
}

// ---- fast: 512 blocks x 64 rows, 4 waves x 16 rows, fp16 MFMA, ~45KB LDS ----
__global__ __launch_bounds__(256, 4)
void vq_fast(const float* __restrict__ z, const float* __restrict__ cb,
             const unsigned short* __restrict__ cbimg,
             const float* __restrict__ Bsg,
             float* __restrict__ zq, float* __restrict__ loss,
             float* __restrict__ idxo,
             unsigned* __restrict__ list, unsigned* __restrict__ cnt,
             float* __restrict__ zdump) {
  __shared__ __align__(16) unsigned char buf[34816]; // zt[256][33]f32 / 2x16KB B / ldsF
  __shared__ float BsL[1024];
  __shared__ float part[32][36];
  __shared__ float rowA[64];
  __shared__ int bestj[64];
  __shared__ float bestd[64];
  __shared__ unsigned char flg[64];
  __shared__ float wred[4];

  const int t = threadIdx.x;
  const int bid = blockIdx.x;          // = bh; rows n0 = bid*64
  const int lane = t & 63;
  const int wv = t >> 6;               // wave 0..3, rows wv*16..+15
  const int l15 = lane & 15;
  const int lk = lane >> 4;            // 0..3

  float* zt = reinterpret_cast<float*>(buf);   // [256 c][33] f32 during A-stage
  const float4* z4 = reinterpret_cast<const float4*>(
      z + (size_t)(bid >> 6) * 1048576 + (size_t)(bid & 63) * 64);

  f16x8 ah[8];
  // ---- A staging in halves of 32 rows (w = hp*32 + w4p*4 + q) ----
  for (int hp = 0; hp < 2; ++hp) {
    float sq[4] = {0.f, 0.f, 0.f, 0.f};
#pragma unroll
    for (int i = 0; i < 8; ++i) {
      int idx = t + i * 256;           // 0..2047: c = idx>>3, w4p = idx&7
      int c = idx >> 3, w4p = idx & 7;
      float4 v = z4[(size_t)c * 1024 + hp * 8 + w4p];
      zt[c * 33 + w4p * 4 + 0] = v.x;
      zt[c * 33 + w4p * 4 + 1] = v.y;
      zt[c * 33 + w4p * 4 + 2] = v.z;
      zt[c * 33 + w4p * 4 + 3] = v.w;
      sq[0] += v.x * v.x; sq[1] += v.y * v.y;
      sq[2] += v.z * v.z; sq[3] += v.w * v.w;
    }
#pragma unroll
    for (int q = 0; q < 4; ++q) part[t >> 3][(t & 7) * 4 + q] = sq[q];
    __syncthreads();
    if (t < 32) {
      float s = 0.f;
#pragma unroll
      for (int g = 0; g < 32; ++g) s += part[g][t];
      rowA[hp * 32 + t] = s;
    }
    // a-frags for waves owning this half (fp16 RNE)
    if ((wv >> 1) == hp) {
      int lr = (wv & 1) * 16 + l15;    // local row in half
#pragma unroll
      for (int kk = 0; kk < 8; ++kk)
#pragma unroll
        for (int m = 0; m < 8; ++m)
          ah[kk][m] = (_Float16)zt[(kk * 32 + lk * 8 + m) * 33 + lr];
    }
    // z-dump (coalesced [n][c]) for the exact pass
    if (zdump) {
#pragma unroll
      for (int i = 0; i < 8; ++i) {
        int item = t + i * 256;        // c4 = item&63, rowp = item>>6 in [0,32)
        int c4 = item & 63, rowp = item >> 6;
        float4 v = make_float4(zt[(c4 * 4 + 0) * 33 + rowp],
                               zt[(c4 * 4 + 1) * 33 + rowp],
                               zt[(c4 * 4 + 2) * 33 + rowp],
                               zt[(c4 * 4 + 3) * 33 + rowp]);
        *reinterpret_cast<float4*>(
            zdump + ((size_t)bid * 64 + hp * 32 + rowp) * 256 + c4 * 4) = v;
      }
    }
    __syncthreads();
  }

  // ---- stage B tile 0 (linear copy; swizzle baked into cbimg) + BsL ----
#pragma unroll
  for (int i = 0; i < 4; ++i) {
    int item = t + i * 256;            // 0..1023 s16x8 items (16 KB)
    *reinterpret_cast<s16x8*>(buf + item * 16) =
        *reinterpret_cast<const s16x8*>((const unsigned char*)cbimg + item * 16);
  }
  for (int i = t; i < 1024; i += 256) BsL[i] = Bsg[i];
  __syncthreads();

  float b1v[2][4], b2v[2][4];
  int b1i[2][4];
#pragma unroll
  for (int js = 0; js < 2; ++js)
#pragma unroll
    for (int r = 0; r < 4; ++r) { b1v[js][r] = 3.4e38f; b2v[js][r] = 3.4e38f; b1i[js][r] = 0; }

  for (int jt = 0; jt < 32; ++jt) {
    const unsigned short* bufH = reinterpret_cast<const unsigned short*>(buf + (jt & 1) * 16384);
    unsigned char* nbuf = buf + ((jt + 1) & 1) * 16384;
    const unsigned char* nsrc = (const unsigned char*)cbimg + (size_t)(jt + 1) * 16384;

    f32x4 acc[2];
    acc[0] = (f32x4){0.f, 0.f, 0.f, 0.f};
    acc[1] = (f32x4){0.f, 0.f, 0.f, 0.f};

    s16x8 g0, g1, g2, g3;
#pragma unroll
    for (int kk = 0; kk < 8; ++kk) {
      if (jt < 31 && kk == 0) {
        g0 = *reinterpret_cast<const s16x8*>(nsrc + (t + 0) * 16);
        g1 = *reinterpret_cast<const s16x8*>(nsrc + (t + 256) * 16);
        g2 = *reinterpret_cast<const s16x8*>(nsrc + (t + 512) * 16);
        g3 = *reinterpret_cast<const s16x8*>(nsrc + (t + 768) * 16);
      }
#pragma unroll
      for (int js = 0; js < 2; ++js) {
        int jj = js * 16 + l15;        // 0..31
        int e = jj * 256 + ((kk * 32 + lk * 8) ^ (jj << 3));
        f16x8 bh = *reinterpret_cast<const f16x8*>(bufH + e);
        acc[js] = __builtin_amdgcn_mfma_f32_16x16x32_f16(ah[kk], bh, acc[js], 0, 0, 0);
      }
      if (jt < 31 && kk == 4) {
        *reinterpret_cast<s16x8*>(nbuf + (t + 0) * 16) = g0;
        *reinterpret_cast<s16x8*>(nbuf + (t + 256) * 16) = g1;
        *reinterpret_cast<s16x8*>(nbuf + (t + 512) * 16) = g2;
        *reinterpret_cast<s16x8*>(nbuf + (t + 768) * 16) = g3;
      }
    }

    // scores: s = B_j - acc/512 ; top-2, ascending j (first-index ties)
#pragma unroll
    for (int js = 0; js < 2; ++js) {
      int j = jt * 32 + js * 16 + l15;
      float Bj = BsL[j];
#pragma unroll
      for (int r = 0; r < 4; ++r) {
        float s = fmaf(SCORE_SCALE, acc[js][r], Bj);
        bool lt = s < b1v[js][r];
        float other = lt ? b1v[js][r] : s;
        b2v[js][r] = fminf(b2v[js][r], other);
        b1v[js][r] = fminf(b1v[js][r], s);
        b1i[js][r] = lt ? j : b1i[js][r];
      }
    }
    __syncthreads();
  }

  // fold js=1 into js=0 (same rows, higher j -> keep first-index ties)
#pragma unroll
  for (int r = 0; r < 4; ++r) {
    float v1 = b1v[1][r];
    bool lt = v1 < b1v[0][r];
    float hi = lt ? b1v[0][r] : v1;
    b2v[0][r] = fminf(fminf(b2v[0][r], b2v[1][r]), hi);
    b1v[0][r] = fminf(b1v[0][r], v1);
    b1i[0][r] = lt ? b1i[1][r] : b1i[0][r];
  }
  // merge across the 16 lanes sharing rows
#pragma unroll
  for (int mk = 1; mk < 16; mk <<= 1) {
#pragma unroll
    for (int r = 0; r < 4; ++r) {
      float ov1 = __shfl_xor(b1v[0][r], mk, 64);
      float ov2 = __shfl_xor(b2v[0][r], mk, 64);
      int oi1 = __shfl_xor(b1i[0][r], mk, 64);
      bool lt = ov1 < b1v[0][r];
      float hi = lt ? b1v[0][r] : ov1;
      b2v[0][r] = fminf(fminf(b2v[0][r], ov2), hi);
      b1v[0][r] = fminf(b1v[0][r], ov1);
      b1i[0][r] = lt ? oi1 : b1i[0][r];
    }
  }
  if (l15 == 0) {
#pragma unroll
    for (int r = 0; r < 4; ++r) {
      int rr = wv * 16 + lk * 4 + r;       // D row = (lane>>4)*4 + reg
      bestj[rr] = b1i[0][r];
      bestd[rr] = b1v[0][r];
      flg[rr] = (b2v[0][r] - b1v[0][r] <= M_GAP) ? 1 : 0;
    }
  }
  __syncthreads();

  if (t < 64) {
    int n = bid * 64 + t;
    idxo[n] = (float)bestj[t];             // provisional for flagged rows
    if (flg[t]) { unsigned pos = atomicAdd(cnt, 1u); list[pos] = (unsigned)n; }
  }

  // loss over ALL rows (flagged rows' provisional s_best is within M_GAP)
  {
    float lv = (t < 64) ? (rowA[t] + bestd[t]) : 0.f;
#pragma unroll
    for (int off = 32; off > 0; off >>= 1) lv += __shfl_down(lv, off, 64);
    if (lane == 0) wred[wv] = lv;
  }
  __syncthreads();
  if (t == 0)
    atomicAdd(loss, (wred[0] + wred[1] + wred[2] + wred[3]) * (1.25f / (float)NELEM));

  // ---- zq gather in halves: cb rows -> LDS transpose -> coalesced write ----
  f32x4* ldsF4 = reinterpret_cast<f32x4*>(buf);
  const float* ldsF = reinterpret_cast<const float*>(buf);
  const float4* cb4 = reinterpret_cast<const float4*>(cb);
  float* zqb = zq + (size_t)(bid >> 6) * 1048576 + (size_t)(bid & 63) * 64;
  for (int hp = 0; hp < 2; ++hp) {
    __syncthreads();
#pragma unroll
    for (int i = 0; i < 8; ++i) {
      int item = t + i * 256;            // rr = item>>6 in [0,32), cc = item&63
      int rr = item >> 6, cc = item & 63;
      float4 v = cb4[(size_t)bestj[hp * 32 + rr] * 64 + cc];
      ldsF4[rr * 64 + (cc ^ ((rr >> 2) & 7))] = (f32x4){v.x, v.y, v.z, v.w};
    }
    __syncthreads();
#pragma unroll
    for (int i = 0; i < 8; ++i) {
      int item = t + i * 256;            // w4p = item&7, c = item>>3
      int w4p = item & 7, c = item >> 3;
      float ov[4];
#pragma unroll
      for (int q = 0; q < 4; ++q) {
        int rr = w4p * 4 + q;
        ov[q] = ldsF[(rr * 64 + ((c >> 2) ^ ((rr >> 2) & 7))) * 4 + (c & 3)];
      }
      *reinterpret_cast<float4*>(zqb + (size_t)c * 4096 + hp * 32 + w4p * 4) =
          make_float4(ov[0], ov[1], ov[2], ov[3]);
    }
  }
}

// ---- exact (fast path): batched 8 rows, reads coalesced zdump, idx-only ----
__global__ __launch_bounds__(256)
void vq_exact_fast(const float* __restrict__ zdump, const float* __restrict__ cbT,
                   const float* __restrict__ Bsg, const unsigned* __restrict__ list,
                   const unsigned* __restrict__ cnt, float* __restrict__ idxo) {
  __shared__ float zr[8][260];
  __shared__ float Anp[8];
  __shared__ float rv[256];
  __shared__ int ri[256];
  const int t = threadIdx.x;
  const unsigned K = *cnt;
  const float4* cbT4 = reinterpret_cast<const float4*>(cbT);
  const float4* zd4 = reinterpret_cast<const float4*>(zdump);

  for (unsigned g = blockIdx.x; g * 8 < K; g += gridDim.x) {
    int nrows = (int)min(8u, K - g * 8);
    __syncthreads();
#pragma unroll
    for (int i = 0; i < 2; ++i) {
      int idx = t + i * 256;             // 0..511: r = idx>>6, c4 = idx&63
      int r = idx >> 6, c4 = idx & 63;
      if (r < nrows) {
        float4 v = zd4[(size_t)list[g * 8 + r] * 64 + c4];
        zr[r][c4 * 4 + 0] = v.x; zr[r][c4 * 4 + 1] = v.y;
        zr[r][c4 * 4 + 2] = v.z; zr[r][c4 * 4 + 3] = v.w;
      }
    }
    __syncthreads();
    if (t < nrows) Anp[t] = np_sumsq256(&zr[t][0], 1);
    __syncthreads();

    float acc[8][4];
#pragma unroll
    for (int r = 0; r < 8; ++r)
#pragma unroll
      for (int q = 0; q < 4; ++q) acc[r][q] = 0.f;
    for (int c = 0; c < 256; ++c) {
      float4 bv = cbT4[c * 256 + t];
#pragma unroll
      for (int r = 0; r < 8; ++r) {
        float zc = zr[r][c];
        acc[r][0] = fmaf(zc, bv.x, acc[r][0]);
        acc[r][1] = fmaf(zc, bv.y, acc[r][1]);
        acc[r][2] = fmaf(zc, bv.z, acc[r][2]);
        acc[r][3] = fmaf(zc, bv.w, acc[r][3]);
      }
    }
    for (int r = 0; r < nrows; ++r) {
      float A = Anp[r];
      float bvv = 3.4e38f;
      int bii = 0;
#pragma unroll
      for (int q = 0; q < 4; ++q) {
        int j = t * 4 + q;
        float dd = __fsub_rn(__fadd_rn(A, Bsg[j]), __fmul_rn(2.0f, acc[r][q]));
        if (dd < bvv) { bvv = dd; bii = j; }
      }
      rv[t] = bvv; ri[t] = bii;
      __syncthreads();
      for (int s2 = 128; s2 > 0; s2 >>= 1) {
        if (t < s2) {
          float v2 = rv[t + s2]; int i2 = ri[t + s2];
          if (v2 < rv[t] || (v2 == rv[t] && i2 < ri[t])) { rv[t] = v2; ri[t] = i2; }
        }
        __syncthreads();
      }
      if (t == 0) idxo[list[g * 8 + r]] = (float)ri[0];
      __syncthreads();
    }
  }
}

// ---- exact (scatter fallback, no zdump): batched 8 rows, idx-only ----
__global__ __launch_bounds__(256)
void vq_exact_scatter(const float* __restrict__ z, const float* __restrict__ cbT,
                      const float* __restrict__ Bsg, const unsigned* __restrict__ list,
                      const unsigned* __restrict__ cnt, float* __restrict__ idxo) {
  __shared__ float zr[8][260];
  __shared__ float Anp[8];
  __shared__ float rv[256];
  __shared__ int ri[256];
  const int t = threadIdx.x;
  const unsigned K = *cnt;
  const float4* cbT4 = reinterpret_cast<const float4*>(cbT);

  for (unsigned g = blockIdx.x; g * 8 < K; g += gridDim.x) {
    int nrows = (int)min(8u, K - g * 8);
    __syncthreads();
    {
      int r = t >> 5, l32 = t & 31;
      if (r < nrows) {
        int n = (int)list[g * 8 + r];
        int b = n >> 12, hw = n & 4095;
        const float* zb = z + (size_t)b * 1048576 + hw;
#pragma unroll
        for (int q = 0; q < 8; ++q) {
          int c = l32 * 8 + q;
          zr[r][c] = zb[(size_t)c * 4096];
        }
      }
    }
    __syncthreads();
    if (t < nrows) Anp[t] = np_sumsq256(&zr[t][0], 1);
    __syncthreads();
    float acc[8][4];
#pragma unroll
    for (int r = 0; r < 8; ++r)
#pragma unroll
      for (int q = 0; q < 4; ++q) acc[r][q] = 0.f;
    for (int c = 0; c < 256; ++c) {
      float4 bv = cbT4[c * 256 + t];
#pragma unroll
      for (int r = 0; r < 8; ++r) {
        float zc = zr[r][c];
        acc[r][0] = fmaf(zc, bv.x, acc[r][0]);
        acc[r][1] = fmaf(zc, bv.y, acc[r][1]);
        acc[r][2] = fmaf(zc, bv.z, acc[r][2]);
        acc[r][3] = fmaf(zc, bv.w, acc[r][3]);
      }
    }
    for (int r = 0; r < nrows; ++r) {
      float A = Anp[r];
      float bvv = 3.4e38f;
      int bii = 0;
#pragma unroll
      for (int q = 0; q < 4; ++q) {
        int j = t * 4 + q;
        float dd = __fsub_rn(__fadd_rn(A, Bsg[j]), __fmul_rn(2.0f, acc[r][q]));
        if (dd < bvv) { bvv = dd; bii = j; }
      }
      rv[t] = bvv; ri[t] = bii;
      __syncthreads();
      for (int s2 = 128; s2 > 0; s2 >>= 1) {
        if (t < s2) {
          float v2 = rv[t + s2]; int i2 = ri[t + s2];
          if (v2 < rv[t] || (v2 == rv[t] && i2 < ri[t])) { rv[t] = v2; ri[t] = i2; }
        }
        __syncthreads();
      }
      if (t == 0) idxo[list[g * 8 + r]] = (float)ri[0];
      __syncthreads();
    }
  }
}

// ---- fallback (round-2 validated all-exact kernel) ----
__global__ __launch_bounds__(256)
void vq_ref(const float* __restrict__ z, const float* __restrict__ cb,
            float* __restrict__ zq, float* __restrict__ loss,
            float* __restrict__ idxo) {
  __shared__ __align__(16) float zt[256 * 64];
  __shared__ __align__(16) float cbt[256 * 64];
  __shared__ float As[64];
  __shared__ float Bs[64];
  __shared__ int bestj[64];
  __shared__ float cand_v[16 * 64];
  __shared__ int cand_i[16 * 64];
  __shared__ double wred[4];
  const int t = threadIdx.x;
  const int wg = t & 15, jg = t >> 4;
  const int bid = blockIdx.x;
  const int b = bid >> 6, h = bid & 63;
  const int n0 = bid * 64;
  const float4* z4 = reinterpret_cast<const float4*>(z + (size_t)b * 256 * 4096 + (size_t)h * 64);
  float4* zt4 = reinterpret_cast<float4*>(zt);
#pragma unroll
  for (int i = 0; i < 16; ++i) {
    int idx4 = t + i * 256;
    zt4[idx4] = z4[(size_t)(idx4 >> 4) * 1024 + (idx4 & 15)];
  }
  __syncthreads();
  if (t < 64) As[t] = np_sumsq256(zt + t, 64);
  float bv[4]; int bi[4];
#pragma unroll
  for (int a = 0; a < 4; ++a) { bv[a] = 3.4e38f; bi[a] = 0; }
  for (int p = 0; p < 16; ++p) {
    __syncthreads();
    const float4* cb4 = reinterpret_cast<const float4*>(cb) + (size_t)p * 64 * 64;
#pragma unroll
    for (int i = 0; i < 16; ++i) {
      int idx4 = t + i * 256;
      int jj = idx4 >> 6, c4 = idx4 & 63;
      float4 v = cb4[idx4];
      cbt[(c4 * 4 + 0) * 64 + jj] = v.x;
      cbt[(c4 * 4 + 1) * 64 + jj] = v.y;
      cbt[(c4 * 4 + 2) * 64 + jj] = v.z;
      cbt[(c4 * 4 + 3) * 64 + jj] = v.w;
    }
    __syncthreads();
    if (t < 64) Bs[t] = np_sumsq256(cbt + t, 64);
    float acc[4][4];
#pragma unroll
    for (int a = 0; a < 4; ++a)
#pragma unroll
      for (int u = 0; u < 4; ++u) acc[a][u] = 0.0f;
    const float4* ztp = reinterpret_cast<const float4*>(zt) + wg;
    const float4* cbp = reinterpret_cast<const float4*>(cbt) + jg;
#pragma unroll 4
    for (int c = 0; c < 256; ++c) {
      float4 zv = ztp[c * 16];
      float4 cv = cbp[c * 16];
      float za[4] = {zv.x, zv.y, zv.z, zv.w};
      float ca[4] = {cv.x, cv.y, cv.z, cv.w};
#pragma unroll
      for (int a = 0; a < 4; ++a)
#pragma unroll
        for (int u = 0; u < 4; ++u) acc[a][u] = fmaf(za[a], ca[u], acc[a][u]);
    }
    __syncthreads();
#pragma unroll
    for (int u = 0; u < 4; ++u) {
      int j = p * 64 + jg * 4 + u;
      float Bju = Bs[jg * 4 + u];
#pragma unroll
      for (int a = 0; a < 4; ++a) {
        float AB = __fadd_rn(As[wg * 4 + a], Bju);
        float dd = __fsub_rn(AB, __fmul_rn(2.0f, acc[a][u]));
        if (dd < bv[a]) { bv[a] = dd; bi[a] = j; }
      }
    }
  }
  __syncthreads();
#pragma unroll
  for (int a = 0; a < 4; ++a) {
    int w = wg * 4 + a;
    cand_v[jg * 64 + w] = bv[a];
    cand_i[jg * 64 + w] = bi[a];
  }
  __syncthreads();
  if (t < 64) {
    float v0 = cand_v[t]; int i0 = cand_i[t];
    for (int g = 1; g < 16; ++g) {
      float v = cand_v[g * 64 + t]; int ii = cand_i[g * 64 + t];
      if (v < v0 || (v == v0 && ii < i0)) { v0 = v; i0 = ii; }
    }
    bestj[t] = i0;
    idxo[n0 + t] = (float)i0;
  }
  __syncthreads();
  double lsum = 0.0;
  float* zqbase = zq + (size_t)b * 256 * 4096 + (size_t)h * 64;
  for (int i = 0; i < 64; ++i) {
    int idx = t + i * 256;
    int c = idx >> 6, w = idx & 63;
    float zvv = zt[c * 64 + w];
    float cvv = cb[(size_t)bestj[w] * 256 + c];
    zqbase[(size_t)c * 4096 + w] = cvv;
    double d = (double)cvv - (double)zvv;
    lsum += d * d;
  }
#pragma unroll
  for (int off = 32; off > 0; off >>= 1) lsum += __shfl_down(lsum, off, 64);
  if ((t & 63) == 0) wred[t >> 6] = lsum;
  __syncthreads();
  if (t == 0) {
    double tot = wred[0] + wred[1] + wred[2] + wred[3];
    atomicAdd(loss, (float)(tot * (1.25 / (double)NELEM)));
  }
}

extern "C" void kernel_launch(void* const* d_in, const int* in_sizes, int n_in,
                              void* d_out, int out_size, void* d_ws, size_t ws_size,
                              hipStream_t stream) {
  (void)in_sizes; (void)n_in; (void)out_size;
  const float* z = (const float*)d_in[0];
  const float* cb = (const float*)d_in[1];
  float* out = (float*)d_out;
  float* zq = out;
  float* loss = out + NELEM;
  float* idxo = out + NELEM + 1;
  if (ws_size < 1712128) {   // scratch too small: validated all-exact path
    hipMemsetAsync(loss, 0, sizeof(float), stream);
    vq_ref<<<512, 256, 0, stream>>>(z, cb, zq, loss, idxo);
    return;
  }
  unsigned char* ws = (unsigned char*)d_ws;
  unsigned* cnt = (unsigned*)ws;                             // 4 B
  float* Bsg = (float*)(ws + 1024);                          // 4 KB
  unsigned* list = (unsigned*)(ws + 8192);                   // 128 KB
  float* cbT = (float*)(ws + 139264);                        // 1 MB
  unsigned short* cbimg = (unsigned short*)(ws + 1187840);   // 512 KB fp16
  const bool have_dump = (ws_size >= 35651584);
  float* zdump = have_dump ? (float*)(ws + 2097152) : nullptr; // 32 MB
  vq_prep<<<16, 256, 0, stream>>>(cb, cbimg, cbT, Bsg, cnt, loss);
  vq_fast<<<512, 256, 0, stream>>>(z, cb, cbimg, Bsg, zq, loss, idxo, list, cnt, zdump);
  if (have_dump)
    vq_exact_fast<<<512, 256, 0, stream>>>(zdump, cbT, Bsg, list, cnt, idxo);
  else
    vq_exact_scatter<<<512, 256, 0, stream>>>(z, cbT, Bsg, list, cnt, idxo);
}